// Round 1
// baseline (447.211 us; speedup 1.0000x reference)
//
#include <hip/hip_runtime.h>
#include <math.h>

// Problem constants: B=8, M=N=256, D=512
#define INFV 1.0e8f

// LDS-only barrier: LDS writes must be visible across the block's 4 waves,
// but no global-memory data crosses threads inside these kernels, so we
// deliberately omit the vmcnt(0) drain that __syncthreads() would emit.
// This lets the per-step global R/cost stores & prefetch loads stay in
// flight across the wavefront steps.
__device__ __forceinline__ void lds_barrier() {
  asm volatile("s_waitcnt lgkmcnt(0)\n\ts_barrier" ::: "memory");
}

// ---------------------------------------------------------------------------
// Kernel 1: inverse row norms.  rn = 1 / max(||row||, 1e-8)
// grid 1024 x 256 threads: one wave (64 lanes) per row, 4096 rows (x then y).
// ---------------------------------------------------------------------------
__global__ void __launch_bounds__(256) norms_kernel(const float* __restrict__ x,
                                                    const float* __restrict__ y,
                                                    float* __restrict__ rnx,
                                                    float* __restrict__ rny) {
  int g = blockIdx.x * 4 + (threadIdx.x >> 6);
  int lane = threadIdx.x & 63;
  const float* src; float* dst; int row;
  if (g < 2048) { src = x; dst = rnx; row = g; }
  else          { src = y; dst = rny; row = g - 2048; }
  const float* p = src + (size_t)row * 512;
  float4 v0 = *(const float4*)(p + lane * 4);
  float4 v1 = *(const float4*)(p + 256 + lane * 4);
  float s = v0.x*v0.x + v0.y*v0.y + v0.z*v0.z + v0.w*v0.w
          + v1.x*v1.x + v1.y*v1.y + v1.z*v1.z + v1.w*v1.w;
#pragma unroll
  for (int o = 32; o > 0; o >>= 1) s += __shfl_xor(s, o, 64);
  if (lane == 0) dst[row] = 1.0f / fmaxf(sqrtf(s), 1e-8f);
}

// ---------------------------------------------------------------------------
// Kernel 2: cost GEMM.  cost[b,m,n] = 1 - dot(x_m,y_n)*rnx[m]*rny[n]
// written in DIAGONAL layout: costD[b][m+n][m]  (diag stride 256, 513 diags
// allocated so the forward kernel's prefetch can harmlessly overrun).
// 64x64 tile / 256 threads / 4x4 micro-tile, fp32 vector ALU.
// ---------------------------------------------------------------------------
__global__ void __launch_bounds__(256) cost_gemm(const float* __restrict__ x,
                                                 const float* __restrict__ y,
                                                 const float* __restrict__ rnx,
                                                 const float* __restrict__ rny,
                                                 float* __restrict__ costD) {
  int b = blockIdx.z, mt = blockIdx.y, nt = blockIdx.x;
  int m0 = mt * 64, n0 = nt * 64;
  __shared__ float Xs[16][68];   // [k][m], pad 68 keeps 16B alignment, 2-way max conflict
  __shared__ float Ys[16][68];   // [k][n]
  int tid = threadIdx.x;
  int row = tid >> 2, cq = tid & 3;      // staging: row 0..63, k-quad 0..3
  int tx = tid & 15, ty = tid >> 4;      // compute: 16x16 thread grid
  const float* xb = x + ((size_t)b * 256 + m0) * 512;
  const float* yb = y + ((size_t)b * 256 + n0) * 512;
  float acc[4][4] = {};
  for (int k0 = 0; k0 < 512; k0 += 16) {
    float4 xv = *(const float4*)(xb + (size_t)row * 512 + k0 + cq * 4);
    float4 yv = *(const float4*)(yb + (size_t)row * 512 + k0 + cq * 4);
    __syncthreads();
    Xs[cq*4+0][row] = xv.x; Xs[cq*4+1][row] = xv.y;
    Xs[cq*4+2][row] = xv.z; Xs[cq*4+3][row] = xv.w;
    Ys[cq*4+0][row] = yv.x; Ys[cq*4+1][row] = yv.y;
    Ys[cq*4+2][row] = yv.z; Ys[cq*4+3][row] = yv.w;
    __syncthreads();
#pragma unroll
    for (int kk = 0; kk < 16; ++kk) {
      float4 av = *(const float4*)(&Xs[kk][ty * 4]);
      float4 bv = *(const float4*)(&Ys[kk][tx * 4]);
      float ar[4] = {av.x, av.y, av.z, av.w};
      float br[4] = {bv.x, bv.y, bv.z, bv.w};
#pragma unroll
      for (int r = 0; r < 4; ++r)
#pragma unroll
        for (int c = 0; c < 4; ++c)
          acc[r][c] += ar[r] * br[c];
    }
  }
  float rx[4], ry[4];
#pragma unroll
  for (int r = 0; r < 4; ++r) rx[r] = rnx[b * 256 + m0 + ty * 4 + r];
#pragma unroll
  for (int c = 0; c < 4; ++c) ry[c] = rny[b * 256 + n0 + tx * 4 + c];
#pragma unroll
  for (int r = 0; r < 4; ++r) {
    int m = m0 + ty * 4 + r;
#pragma unroll
    for (int c = 0; c < 4; ++c) {
      int n = n0 + tx * 4 + c;
      costD[((size_t)b * 513 + (m + n)) * 256 + m] = 1.0f - acc[r][c] * rx[r] * ry[c];
    }
  }
}

// ---------------------------------------------------------------------------
// Kernel 3: forward soft-DTW.  One block per batch, 256 threads, thread t
// owns R-cell i = t+1 on each anti-diagonal dr = i+j (dr = 2..512).
// Rolling 3 diagonals in LDS; every computed R value also streamed to global
// RdG[b][dr][i] (diag stride 257) for the backward pass; cost prefetched
// 2 deep into registers.  Cell valid iff j = dr-i in [1,256].
// ---------------------------------------------------------------------------
__global__ void __launch_bounds__(256) fwd_kernel(const float* __restrict__ costD,
                                                  const float* __restrict__ gamma,
                                                  float* __restrict__ RdG,
                                                  float* __restrict__ dist_out) {
  int b = blockIdx.x, t = threadIdx.x;
  __shared__ float Rb[3][257];
  float gv = fmaxf(fabsf(gamma[0]), 1e-4f);
  float ig = 1.0f / gv;
  for (int k = t; k < 3 * 257; k += 256) (&Rb[0][0])[k] = INFV;
  __syncthreads();
  if (t == 0) Rb[0][0] = 0.0f;   // R[0][0] = 0 (diag 0)
  const float* cb = costD + (size_t)b * 513 * 256;
  float* Rg = RdG + (size_t)b * 513 * 257;
  float ccur  = cb[t];           // cost diag 0 (for dr=2)
  float cnext = cb[256 + t];     // cost diag 1 (for dr=3)
  __syncthreads();
  float* Rcur = &Rb[2][0];       // diag dr (write)
  float* Rp1  = &Rb[1][0];       // diag dr-1
  float* Rp2  = &Rb[0][0];       // diag dr-2
  for (int dr = 2; dr <= 512; ++dr) {
    float a   = Rp1[t];          // R[i-1][j]
    float bbv = Rp1[t + 1];      // R[i][j-1]
    float c   = Rp2[t];          // R[i-1][j-1]
    float mn = fminf(a, fminf(bbv, c));
    float s = __expf((mn - a) * ig) + __expf((mn - bbv) * ig) + __expf((mn - c) * ig);
    float val = ccur + mn - gv * __logf(s);
    int j = dr - (t + 1);
    if (j >= 1 && j <= 256) {
      Rcur[t + 1] = val;
      Rg[(size_t)dr * 257 + t + 1] = val;
    }
    if (t == 0) Rcur[0] = INFV;              // R[0][dr] boundary
    if (dr == 512 && t == 255) dist_out[b] = val;   // distance = R[256][256]
    ccur = cnext;
    cnext = cb[(size_t)dr * 256 + t];        // cost diag dr (for iter dr+2)
    float* tmp = Rp2; Rp2 = Rp1; Rp1 = Rcur; Rcur = tmp;
    lds_barrier();
  }
}

// ---------------------------------------------------------------------------
// Kernel 4: backward soft-DTW (alignment gradients E).  Same wavefront,
// dr = 511 down to 2.  LDS: R rolling depth-4, cost depth-3, E depth-3 --
// depths chosen so a single barrier per step suffices (the buffer being
// overwritten is never read in the same step).  R/cost prefetched 2 deep.
// E written in diagonal layout EdG[b][dr-2][i-1]; corner seed E=1 preset.
// ---------------------------------------------------------------------------
__global__ void __launch_bounds__(256) bwd_kernel(const float* __restrict__ costD,
                                                  const float* __restrict__ RdG,
                                                  const float* __restrict__ gamma,
                                                  float* __restrict__ EdG) {
  int b = blockIdx.x, t = threadIdx.x;
  __shared__ float Rs[4][258];
  __shared__ float Cs[3][257];
  __shared__ float Es[3][258];
  float gv = fmaxf(fabsf(gamma[0]), 1e-4f);
  float ig = 1.0f / gv;
  const float* Rg = RdG + (size_t)b * 513 * 257;
  const float* cb = costD + (size_t)b * 513 * 256;
  float* Eg = EdG + (size_t)b * 511 * 256;
  // issue preloads early
  float dist = Rg[512 * 257 + 256];
  float r511 = Rg[511 * 257 + t + 1];
  float c510 = cb[510 * 256 + t];
  float pR1 = Rg[510 * 257 + t + 1];
  float pR0 = Rg[509 * 257 + t + 1];
  float pC1 = cb[509 * 256 + t];
  float pC0 = cb[508 * 256 + t];
  for (int k = t; k < 4 * 258; k += 256) (&Rs[0][0])[k] = -INFV;
  for (int k = t; k < 3 * 258; k += 256) (&Es[0][0])[k] = 0.0f;
  __syncthreads();
  Rs[3][t + 1] = r511;           // R diag 511  (511%4==3)
  Cs[0][t] = c510;               // C diag 510  (510%3==0)
  if (t == 255) {
    Rs[0][256] = dist;           // R diag 512 corner (512%4==0)
    Es[2][256] = 1.0f;           // E[256][256] = 1 seed (512%3==2)
    Eg[510 * 256 + 255] = 1.0f;  // corner of alignment output
  }
  __syncthreads();
  float* pRc  = &Rs[3][0];  // R[dr]
  float* pR1v = &Rs[0][0];  // R[dr+1]
  float* pR2v = &Rs[1][0];  // R[dr+2]
  float* pRw  = &Rs[2][0];  // write R[dr-1]
  float* pEw  = &Es[1][0];  // write E[dr]
  float* pE1  = &Es[2][0];  // E[dr+1]
  float* pE2  = &Es[0][0];  // E[dr+2]
  float* pCc  = &Cs[1][0];  // C[dr]   (garbage at dr=511: guarded unused)
  float* pCp  = &Cs[0][0];  // C[dr-1]
  float* pCw  = &Cs[2][0];  // write C[dr-2]
  for (int dr = 511; dr >= 2; --dr) {
    int i = t + 1, j = dr - i;
    float rc = pRc[t + 1];                                   // R[i][j]
    float rd = pR2v[t + 2], ed = pE2[t + 2], cd = pCc[t + 1]; // (i+1,j+1)
    float rn = pR1v[t + 2], en = pE1[t + 2], cn = pCp[t + 1]; // (i+1,j)
    float rr = pR1v[t + 1], er = pE1[t + 1], cr = pCp[t];     // (i,j+1)
    bool ok_i = (i <= 255), ok_j = (j <= 255);
    float wd = __expf(fminf(fmaxf((rd - cd - rc) * ig, -50.f), 50.f));
    float wn = __expf(fminf(fmaxf((rn - cn - rc) * ig, -50.f), 50.f));
    float wr = __expf(fminf(fmaxf((rr - cr - rc) * ig, -50.f), 50.f));
    float e = ((ok_i && ok_j) ? ed * wd : 0.f)
            + (ok_i ? en * wn : 0.f)
            + (ok_j ? er * wr : 0.f);
    if (j >= 1 && j <= 256) {
      pEw[t + 1] = e;
      Eg[(size_t)(dr - 2) * 256 + t] = e;
    }
    pRw[t + 1] = pR1;  pR1 = pR0;    // commit prefetched R[dr-1]
    pCw[t] = pC1;      pC1 = pC0;    // commit prefetched C[dr-2]
    int iR = dr - 3 > 0 ? dr - 3 : 0;
    int iC = dr - 4 > 0 ? dr - 4 : 0;
    pR0 = Rg[(size_t)iR * 257 + t + 1];
    pC0 = cb[(size_t)iC * 256 + t];
    float* tR = pR2v; pR2v = pR1v; pR1v = pRc; pRc = pRw; pRw = tR;
    float* tE = pE2;  pE2 = pE1;  pE1 = pEw;  pEw = tE;
    float* tC = pCc;  pCc = pCp;  pCp = pCw;  pCw = tC;
    lds_barrier();
  }
}

// ---------------------------------------------------------------------------
// Kernel 5: diagonal -> row-major transpose of the alignment.
// alignment[b][m][n] = EdG[b][m+n][m].  64x64 output tile per block via an
// LDS tile (row pad 65 => conflict-free stride-65 reads in phase 2).
// ---------------------------------------------------------------------------
__global__ void __launch_bounds__(256) transpose_kernel(const float* __restrict__ EdG,
                                                        float* __restrict__ out) {
  int b = blockIdx.z, mt = blockIdx.y, nt = blockIdx.x;
  int m0 = mt * 64, n0 = nt * 64;
  __shared__ float T[127][65];
  const float* Eg = EdG + (size_t)b * 511 * 256;
  int dc0 = m0 + n0;
  for (int k = threadIdx.x; k < 127 * 64; k += 256) {
    int dcl = k >> 6, mm = k & 63;
    T[dcl][mm] = Eg[(size_t)(dc0 + dcl) * 256 + m0 + mm];
  }
  __syncthreads();
  float* ob = out + ((size_t)b * 256 + m0) * 256 + n0;
  for (int k = threadIdx.x; k < 4096; k += 256) {
    int r = k >> 6, c = k & 63;
    ob[(size_t)r * 256 + c] = T[r + c][r];
  }
}

// ---------------------------------------------------------------------------
// Workspace layout (floats):
//   rnx   @ 0          (2048)
//   rny   @ 2048       (2048)
//   costD @ 4096       (8*513*256 = 1,050,624)   diag-major cost
//   RdG   @ 1,054,720  (8*513*257 = 1,054,728)   diag-major R
//   EdG   @ 2,109,448  (8*511*256 = 1,046,528)   diag-major E
// total ~12.6 MB.
// d_out: alignment [0 .. 524287], distance [524288 .. 524295].
// ---------------------------------------------------------------------------
extern "C" void kernel_launch(void* const* d_in, const int* in_sizes, int n_in,
                              void* d_out, int out_size, void* d_ws, size_t ws_size,
                              hipStream_t stream) {
  const float* x = (const float*)d_in[0];
  const float* y = (const float*)d_in[1];
  const float* gamma = (const float*)d_in[2];
  float* out = (float*)d_out;
  float* ws = (float*)d_ws;

  float* rnx   = ws;
  float* rny   = ws + 2048;
  float* costD = ws + 4096;
  float* RdG   = costD + (size_t)8 * 513 * 256;
  float* EdG   = RdG   + (size_t)8 * 513 * 257;

  norms_kernel<<<1024, 256, 0, stream>>>(x, y, rnx, rny);
  cost_gemm<<<dim3(4, 4, 8), 256, 0, stream>>>(x, y, rnx, rny, costD);
  fwd_kernel<<<8, 256, 0, stream>>>(costD, gamma, RdG, out + 524288);
  bwd_kernel<<<8, 256, 0, stream>>>(costD, RdG, gamma, EdG);
  transpose_kernel<<<dim3(4, 4, 8), 256, 0, stream>>>(EdG, out);
}

// Round 3
// 355.449 us; speedup vs baseline: 1.2582x; 1.2582x over previous
//
#include <hip/hip_runtime.h>

// Problem constants: B=8, M=N=256, D=512
#define INFV 1.0e8f
#define CD_DIAGS 512   // cost diag slots (valid diags 0..510, +1 pad for prefetch)
#define RD_DIAGS 514   // R diag slots (valid 0..512, +1 pad)
#define RD_STRIDE 260  // floats per R diag: 257 rounded to 16B multiple

// Raw HW transcendentals: v_exp_f32 is 2^x, v_log_f32 is log2(x).
#define EXP2F(x) __builtin_amdgcn_exp2f(x)
#define LOG2F(x) __builtin_amdgcn_logf(x)

__device__ __forceinline__ void ld4(float d[4], const float* p) {
  float4 v = *(const float4*)p;
  d[0] = v.x; d[1] = v.y; d[2] = v.z; d[3] = v.w;
}
__device__ __forceinline__ void cp4(float d[4], const float s[4]) {
#pragma unroll
  for (int k = 0; k < 4; ++k) d[k] = s[k];
}

// ---------------------------------------------------------------------------
// Kernel 1: inverse row norms.  rn = 1 / max(||row||, 1e-8)
// ---------------------------------------------------------------------------
__global__ void __launch_bounds__(256) norms_kernel(const float* __restrict__ x,
                                                    const float* __restrict__ y,
                                                    float* __restrict__ rnx,
                                                    float* __restrict__ rny) {
  int g = blockIdx.x * 4 + (threadIdx.x >> 6);
  int lane = threadIdx.x & 63;
  const float* src; float* dst; int row;
  if (g < 2048) { src = x; dst = rnx; row = g; }
  else          { src = y; dst = rny; row = g - 2048; }
  const float* p = src + (size_t)row * 512;
  float4 v0 = *(const float4*)(p + lane * 4);
  float4 v1 = *(const float4*)(p + 256 + lane * 4);
  float s = v0.x*v0.x + v0.y*v0.y + v0.z*v0.z + v0.w*v0.w
          + v1.x*v1.x + v1.y*v1.y + v1.z*v1.z + v1.w*v1.w;
#pragma unroll
  for (int o = 32; o > 0; o >>= 1) s += __shfl_xor(s, o, 64);
  if (lane == 0) dst[row] = 1.0f / fmaxf(sqrtf(s), 1e-8f);
}

// ---------------------------------------------------------------------------
// Kernel 2: cost GEMM -> diagonal layout costD[b][m+n][m], diag stride 256.
// ---------------------------------------------------------------------------
__global__ void __launch_bounds__(256) cost_gemm(const float* __restrict__ x,
                                                 const float* __restrict__ y,
                                                 const float* __restrict__ rnx,
                                                 const float* __restrict__ rny,
                                                 float* __restrict__ costD) {
  int b = blockIdx.z, mt = blockIdx.y, nt = blockIdx.x;
  int m0 = mt * 64, n0 = nt * 64;
  __shared__ float Xs[16][68];
  __shared__ float Ys[16][68];
  int tid = threadIdx.x;
  int row = tid >> 2, cq = tid & 3;
  int tx = tid & 15, ty = tid >> 4;
  const float* xb = x + ((size_t)b * 256 + m0) * 512;
  const float* yb = y + ((size_t)b * 256 + n0) * 512;
  float acc[4][4] = {};
  for (int k0 = 0; k0 < 512; k0 += 16) {
    float4 xv = *(const float4*)(xb + (size_t)row * 512 + k0 + cq * 4);
    float4 yv = *(const float4*)(yb + (size_t)row * 512 + k0 + cq * 4);
    __syncthreads();
    Xs[cq*4+0][row] = xv.x; Xs[cq*4+1][row] = xv.y;
    Xs[cq*4+2][row] = xv.z; Xs[cq*4+3][row] = xv.w;
    Ys[cq*4+0][row] = yv.x; Ys[cq*4+1][row] = yv.y;
    Ys[cq*4+2][row] = yv.z; Ys[cq*4+3][row] = yv.w;
    __syncthreads();
#pragma unroll
    for (int kk = 0; kk < 16; ++kk) {
      float4 av = *(const float4*)(&Xs[kk][ty * 4]);
      float4 bv = *(const float4*)(&Ys[kk][tx * 4]);
      float ar[4] = {av.x, av.y, av.z, av.w};
      float br[4] = {bv.x, bv.y, bv.z, bv.w};
#pragma unroll
      for (int r = 0; r < 4; ++r)
#pragma unroll
        for (int c = 0; c < 4; ++c)
          acc[r][c] += ar[r] * br[c];
    }
  }
  float rx[4], ry[4];
#pragma unroll
  for (int r = 0; r < 4; ++r) rx[r] = rnx[b * 256 + m0 + ty * 4 + r];
#pragma unroll
  for (int c = 0; c < 4; ++c) ry[c] = rny[b * 256 + n0 + tx * 4 + c];
#pragma unroll
  for (int r = 0; r < 4; ++r) {
    int m = m0 + ty * 4 + r;
#pragma unroll
    for (int c = 0; c < 4; ++c) {
      int n = n0 + tx * 4 + c;
      costD[((size_t)b * CD_DIAGS + (m + n)) * 256 + m] = 1.0f - acc[r][c] * rx[r] * ry[c];
    }
  }
}

// ---------------------------------------------------------------------------
// Kernel 3: forward soft-DTW.  ONE WAVE per batch; lane l owns rows
// i = 4l+1..4l+4.  All cross-lane comm via shuffles (no LDS, no barriers).
// Cost diag prefetched 4 steps ahead in a register FIFO (manual unroll x4).
// R written per diag to RdG[b][dr][i-1] (stride RD_STRIDE, aligned float4).
// ---------------------------------------------------------------------------
__device__ __forceinline__ void fwd_step(int dr, int l, const float cc[4],
                                         float rp1[4], float rp2[4],
                                         float ig2, float gl,
                                         float* __restrict__ Rg,
                                         float* __restrict__ dist) {
  float up1 = __shfl_up(rp1[3], 1);
  float up2 = __shfl_up(rp2[3], 1);
  if (l == 0) { up1 = INFV; up2 = (dr == 2) ? 0.0f : INFV; }
  float val[4];
#pragma unroll
  for (int k = 0; k < 4; ++k) {
    float a  = k ? rp1[k-1] : up1;   // R[i-1][j]
    float bb = rp1[k];               // R[i][j-1]
    float c  = k ? rp2[k-1] : up2;   // R[i-1][j-1]
    float mn = fminf(a, fminf(bb, c));
    float s = EXP2F((mn - a) * ig2) + EXP2F((mn - bb) * ig2)
            + EXP2F((mn - c) * ig2);
    float v = cc[k] + mn - gl * LOG2F(s);
    int i = 4 * l + 1 + k, j = dr - i;
    val[k] = (j >= 1 && j <= 256) ? v : INFV;
  }
  if (dr == 512 && l == 63) dist[0] = val[3];
#pragma unroll
  for (int k = 0; k < 4; ++k) { rp2[k] = rp1[k]; rp1[k] = val[k]; }
  float4 st = {val[0], val[1], val[2], val[3]};
  *(float4*)(Rg + (size_t)dr * RD_STRIDE + 4 * l) = st;
}

__global__ void __launch_bounds__(64) fwd_kernel(const float* __restrict__ costD,
                                                 const float* __restrict__ gamma,
                                                 float* __restrict__ RdG,
                                                 float* __restrict__ dist_out) {
  int b = blockIdx.x, l = threadIdx.x;
  float gv = fmaxf(fabsf(gamma[0]), 1e-4f);
  const float LOG2E = 1.4426950408889634f;
  float ig2 = LOG2E / gv;                 // exponent scale for exp2
  float gl  = gv * 0.6931471805599453f;   // gv*ln2: gv*ln(s) = gl*log2(s)
  const float* cb = costD + (size_t)b * CD_DIAGS * 256;
  float* Rg = RdG + (size_t)b * RD_DIAGS * RD_STRIDE;
  float* dist = dist_out + b;
  float rp1[4], rp2[4];
#pragma unroll
  for (int k = 0; k < 4; ++k) { rp1[k] = INFV; rp2[k] = INFV; }
  float c0[4], c1[4], c2[4], c3[4];
  ld4(c0, cb + 0 * 256 + 4 * l);
  ld4(c1, cb + 1 * 256 + 4 * l);
  ld4(c2, cb + 2 * 256 + 4 * l);
  ld4(c3, cb + 3 * 256 + 4 * l);
  int dr = 2;
  for (int g = 0; g < 127; ++g) {
    fwd_step(dr + 0, l, c0, rp1, rp2, ig2, gl, Rg, dist);
    ld4(c0, cb + (size_t)(dr + 2) * 256 + 4 * l);
    fwd_step(dr + 1, l, c1, rp1, rp2, ig2, gl, Rg, dist);
    ld4(c1, cb + (size_t)(dr + 3) * 256 + 4 * l);
    fwd_step(dr + 2, l, c2, rp1, rp2, ig2, gl, Rg, dist);
    ld4(c2, cb + (size_t)(dr + 4) * 256 + 4 * l);
    fwd_step(dr + 3, l, c3, rp1, rp2, ig2, gl, Rg, dist);
    ld4(c3, cb + (size_t)(dr + 5) * 256 + 4 * l);
    dr += 4;
  }
  // dr == 510: last three diagonals, FIFO already holds diags 508,509,510
  fwd_step(510, l, c0, rp1, rp2, ig2, gl, Rg, dist);
  fwd_step(511, l, c1, rp1, rp2, ig2, gl, Rg, dist);
  fwd_step(512, l, c2, rp1, rp2, ig2, gl, Rg, dist);
}

// ---------------------------------------------------------------------------
// Kernel 4: backward soft-DTW.  Same one-wave-per-batch, shuffle-only comm.
// Rolling register diags: R (dr,dr+1,dr+2), cost (dr,dr-1), E (dr+1,dr+2).
// R and cost prefetched via 4-deep register FIFOs.  E stored in diag layout
// EdG[b][dr-2][i-1].
// ---------------------------------------------------------------------------
__device__ __forceinline__ void bwd_step(int dr, int l,
    const float rA[4], const float rB[4], const float rC[4],
    const float cD[4], const float cD1[4],
    float eN[4], float eN2[4],
    float ig2, float CL, float* __restrict__ Eg) {
  float rBu  = __shfl_down(rB[0], 1);
  float rCu  = __shfl_down(rC[0], 1);
  float cDu  = __shfl_down(cD[0], 1);
  float cD1u = __shfl_down(cD1[0], 1);
  float eNu  = __shfl_down(eN[0], 1);
  float eN2u = __shfl_down(eN2[0], 1);
  float e[4];
#pragma unroll
  for (int k = 0; k < 4; ++k) {
    int i = 4 * l + 1 + k, j = dr - i;
    float rc = rA[k];                          // R[i][j]
    float rd = (k < 3) ? rC[k+1] : rCu;        // R[i+1][j+1]
    float rn = (k < 3) ? rB[k+1] : rBu;        // R[i+1][j]
    float rr = rB[k];                          // R[i][j+1]
    float cd = (k < 3) ? cD[k+1] : cDu;        // cost[i][j]
    float cn = (k < 3) ? cD1[k+1] : cD1u;      // cost[i][j-1]
    float cr = cD1[k];                         // cost[i-1][j]
    float ed = (k < 3) ? eN2[k+1] : eN2u;      // E[i+1][j+1]
    float en = (k < 3) ? eN[k+1] : eNu;        // E[i+1][j]
    float er = eN[k];                          // E[i][j+1]
    float wd = EXP2F(fminf(fmaxf((rd - cd - rc) * ig2, -CL), CL));
    float wn = EXP2F(fminf(fmaxf((rn - cn - rc) * ig2, -CL), CL));
    float wr = EXP2F(fminf(fmaxf((rr - cr - rc) * ig2, -CL), CL));
    bool oki = (i <= 255), okj = (j <= 255);
    float v = ((oki && okj) ? ed * wd : 0.0f)
            + (oki ? en * wn : 0.0f)
            + (okj ? er * wr : 0.0f);
    e[k] = (j >= 1 && j <= 256) ? v : 0.0f;
  }
#pragma unroll
  for (int k = 0; k < 4; ++k) { eN2[k] = eN[k]; eN[k] = e[k]; }
  float4 st = {e[0], e[1], e[2], e[3]};
  *(float4*)(Eg + (size_t)(dr - 2) * 256 + 4 * l) = st;
}

__global__ void __launch_bounds__(64) bwd_kernel(const float* __restrict__ costD,
                                                 const float* __restrict__ RdG,
                                                 const float* __restrict__ gamma,
                                                 float* __restrict__ EdG) {
  int b = blockIdx.x, l = threadIdx.x;
  float gv = fmaxf(fabsf(gamma[0]), 1e-4f);
  const float LOG2E = 1.4426950408889634f;
  float ig2 = LOG2E / gv;
  const float CL = 50.0f * LOG2E;   // clip(+-50) in exp2 units
  const float* Rg = RdG + (size_t)b * RD_DIAGS * RD_STRIDE;
  const float* cb = costD + (size_t)b * CD_DIAGS * 256;
  float* Eg = EdG + (size_t)b * 511 * 256;
  // R diag registers + 4-deep FIFO
  float rA[4], rB[4], rC[4], f0[4], f1[4], f2[4], f3[4];
  ld4(rA, Rg + (size_t)511 * RD_STRIDE + 4 * l);
  ld4(rB, Rg + (size_t)512 * RD_STRIDE + 4 * l);
  ld4(rC, Rg + (size_t)513 * RD_STRIDE + 4 * l);
  ld4(f0, Rg + (size_t)510 * RD_STRIDE + 4 * l);
  ld4(f1, Rg + (size_t)509 * RD_STRIDE + 4 * l);
  ld4(f2, Rg + (size_t)508 * RD_STRIDE + 4 * l);
  ld4(f3, Rg + (size_t)507 * RD_STRIDE + 4 * l);
  // cost diag registers + 4-deep FIFO
  float cD[4], cD1[4], q0[4], q1[4], q2[4], q3[4];
  ld4(cD,  cb + (size_t)511 * 256 + 4 * l);
  ld4(cD1, cb + (size_t)510 * 256 + 4 * l);
  ld4(q0,  cb + (size_t)509 * 256 + 4 * l);
  ld4(q1,  cb + (size_t)508 * 256 + 4 * l);
  ld4(q2,  cb + (size_t)507 * 256 + 4 * l);
  ld4(q3,  cb + (size_t)506 * 256 + 4 * l);
  // E seed: diag 512 has only E[256][256] = 1
  float eN[4] = {0.f, 0.f, 0.f, 0.f}, eN2[4] = {0.f, 0.f, 0.f, 0.f};
  if (l == 63) {
    eN[3] = 1.0f;
    Eg[510 * 256 + 255] = 1.0f;   // alignment corner (E diag 512)
  }
  int dr = 511;
  for (int g = 0; g < 127; ++g) {
    bwd_step(dr - 0, l, rA, rB, rC, cD, cD1, eN, eN2, ig2, CL, Eg);
    cp4(rC, rB); cp4(rB, rA); cp4(rA, f0);
    ld4(f0, Rg + (size_t)max(dr - 5, 0) * RD_STRIDE + 4 * l);
    cp4(cD, cD1); cp4(cD1, q0);
    ld4(q0, cb + (size_t)max(dr - 6, 0) * 256 + 4 * l);
    bwd_step(dr - 1, l, rA, rB, rC, cD, cD1, eN, eN2, ig2, CL, Eg);
    cp4(rC, rB); cp4(rB, rA); cp4(rA, f1);
    ld4(f1, Rg + (size_t)max(dr - 6, 0) * RD_STRIDE + 4 * l);
    cp4(cD, cD1); cp4(cD1, q1);
    ld4(q1, cb + (size_t)max(dr - 7, 0) * 256 + 4 * l);
    bwd_step(dr - 2, l, rA, rB, rC, cD, cD1, eN, eN2, ig2, CL, Eg);
    cp4(rC, rB); cp4(rB, rA); cp4(rA, f2);
    ld4(f2, Rg + (size_t)max(dr - 7, 0) * RD_STRIDE + 4 * l);
    cp4(cD, cD1); cp4(cD1, q2);
    ld4(q2, cb + (size_t)max(dr - 8, 0) * 256 + 4 * l);
    bwd_step(dr - 3, l, rA, rB, rC, cD, cD1, eN, eN2, ig2, CL, Eg);
    cp4(rC, rB); cp4(rB, rA); cp4(rA, f3);
    ld4(f3, Rg + (size_t)max(dr - 8, 0) * RD_STRIDE + 4 * l);
    cp4(cD, cD1); cp4(cD1, q3);
    ld4(q3, cb + (size_t)max(dr - 9, 0) * 256 + 4 * l);
    dr -= 4;
  }
  // dr == 3: two remaining diagonals; FIFOs hold diags 2 (R) and 1 (cost)
  bwd_step(3, l, rA, rB, rC, cD, cD1, eN, eN2, ig2, CL, Eg);
  cp4(rC, rB); cp4(rB, rA); cp4(rA, f0);
  cp4(cD, cD1); cp4(cD1, q0);
  bwd_step(2, l, rA, rB, rC, cD, cD1, eN, eN2, ig2, CL, Eg);
}

// ---------------------------------------------------------------------------
// Kernel 5: diagonal -> row-major transpose of the alignment.
// ---------------------------------------------------------------------------
__global__ void __launch_bounds__(256) transpose_kernel(const float* __restrict__ EdG,
                                                        float* __restrict__ out) {
  int b = blockIdx.z, mt = blockIdx.y, nt = blockIdx.x;
  int m0 = mt * 64, n0 = nt * 64;
  __shared__ float T[127][65];
  const float* Eg = EdG + (size_t)b * 511 * 256;
  int dc0 = m0 + n0;
  for (int k = threadIdx.x; k < 127 * 64; k += 256) {
    int dcl = k >> 6, mm = k & 63;
    T[dcl][mm] = Eg[(size_t)(dc0 + dcl) * 256 + m0 + mm];
  }
  __syncthreads();
  float* ob = out + ((size_t)b * 256 + m0) * 256 + n0;
  for (int k = threadIdx.x; k < 4096; k += 256) {
    int r = k >> 6, c = k & 63;
    ob[(size_t)r * 256 + c] = T[r + c][r];
  }
}

// ---------------------------------------------------------------------------
// Workspace layout (floats):
//   rnx   @ 0                      (2048)
//   rny   @ 2048                   (2048)
//   costD @ 4096                   (8*512*256 = 1,048,576)
//   RdG   @ costD + 8*512*256      (8*514*260 = 1,069,120)
//   EdG   @ RdG   + 8*514*260      (8*511*256 = 1,046,528)
// total ~12.68 MB.
// d_out: alignment [0 .. 524287], distance [524288 .. 524295].
// ---------------------------------------------------------------------------
extern "C" void kernel_launch(void* const* d_in, const int* in_sizes, int n_in,
                              void* d_out, int out_size, void* d_ws, size_t ws_size,
                              hipStream_t stream) {
  const float* x = (const float*)d_in[0];
  const float* y = (const float*)d_in[1];
  const float* gamma = (const float*)d_in[2];
  float* out = (float*)d_out;
  float* ws = (float*)d_ws;

  float* rnx   = ws;
  float* rny   = ws + 2048;
  float* costD = ws + 4096;
  float* RdG   = costD + (size_t)8 * CD_DIAGS * 256;
  float* EdG   = RdG   + (size_t)8 * RD_DIAGS * RD_STRIDE;

  norms_kernel<<<1024, 256, 0, stream>>>(x, y, rnx, rny);
  cost_gemm<<<dim3(4, 4, 8), 256, 0, stream>>>(x, y, rnx, rny, costD);
  fwd_kernel<<<8, 64, 0, stream>>>(costD, gamma, RdG, out + 524288);
  bwd_kernel<<<8, 64, 0, stream>>>(costD, RdG, gamma, EdG);
  transpose_kernel<<<dim3(4, 4, 8), 256, 0, stream>>>(EdG, out);
}

// Round 4
// 270.208 us; speedup vs baseline: 1.6551x; 1.3155x over previous
//
#include <hip/hip_runtime.h>

// Problem constants: B=8, M=N=256, D=512
#define INFV 1.0e8f
#define CD_DIAGS 512   // cost diag slots (valid diags 0..510, +1 pad)
#define RD_DIAGS 514   // R(q) diag slots (valid 2..512, 513 = clamp pad)
#define RD_STRIDE 260  // floats per R diag: 257 rounded to 16B multiple
#define WD_DIAGS 512   // weight/E diag slots (valid 0..509, 510 = corner seed)

// Raw HW transcendentals: v_exp_f32 is 2^x, v_log_f32 is log2(x).
#define EXP2F(x) __builtin_amdgcn_exp2f(x)
#define LOG2F(x) __builtin_amdgcn_logf(x)

__device__ __forceinline__ void ld4(float d[4], const float* p) {
  float4 v = *(const float4*)p;
  d[0] = v.x; d[1] = v.y; d[2] = v.z; d[3] = v.w;
}
__device__ __forceinline__ void cp4(float d[4], const float s[4]) {
#pragma unroll
  for (int k = 0; k < 4; ++k) d[k] = s[k];
}

// ---------------------------------------------------------------------------
// Kernel 1: inverse row norms.  rn = 1 / max(||row||, 1e-8)
// ---------------------------------------------------------------------------
__global__ void __launch_bounds__(256) norms_kernel(const float* __restrict__ x,
                                                    const float* __restrict__ y,
                                                    float* __restrict__ rnx,
                                                    float* __restrict__ rny) {
  int g = blockIdx.x * 4 + (threadIdx.x >> 6);
  int lane = threadIdx.x & 63;
  const float* src; float* dst; int row;
  if (g < 2048) { src = x; dst = rnx; row = g; }
  else          { src = y; dst = rny; row = g - 2048; }
  const float* p = src + (size_t)row * 512;
  float4 v0 = *(const float4*)(p + lane * 4);
  float4 v1 = *(const float4*)(p + 256 + lane * 4);
  float s = v0.x*v0.x + v0.y*v0.y + v0.z*v0.z + v0.w*v0.w
          + v1.x*v1.x + v1.y*v1.y + v1.z*v1.z + v1.w*v1.w;
#pragma unroll
  for (int o = 32; o > 0; o >>= 1) s += __shfl_xor(s, o, 64);
  if (lane == 0) dst[row] = 1.0f / fmaxf(sqrtf(s), 1e-8f);
}

// ---------------------------------------------------------------------------
// Kernel 2: cost GEMM -> diagonal layout costD[b][m+n][m], diag stride 256.
// ---------------------------------------------------------------------------
__global__ void __launch_bounds__(256) cost_gemm(const float* __restrict__ x,
                                                 const float* __restrict__ y,
                                                 const float* __restrict__ rnx,
                                                 const float* __restrict__ rny,
                                                 float* __restrict__ costD) {
  int b = blockIdx.z, mt = blockIdx.y, nt = blockIdx.x;
  int m0 = mt * 64, n0 = nt * 64;
  __shared__ float Xs[16][68];
  __shared__ float Ys[16][68];
  int tid = threadIdx.x;
  int row = tid >> 2, cq = tid & 3;
  int tx = tid & 15, ty = tid >> 4;
  const float* xb = x + ((size_t)b * 256 + m0) * 512;
  const float* yb = y + ((size_t)b * 256 + n0) * 512;
  float acc[4][4] = {};
  for (int k0 = 0; k0 < 512; k0 += 16) {
    float4 xv = *(const float4*)(xb + (size_t)row * 512 + k0 + cq * 4);
    float4 yv = *(const float4*)(yb + (size_t)row * 512 + k0 + cq * 4);
    __syncthreads();
    Xs[cq*4+0][row] = xv.x; Xs[cq*4+1][row] = xv.y;
    Xs[cq*4+2][row] = xv.z; Xs[cq*4+3][row] = xv.w;
    Ys[cq*4+0][row] = yv.x; Ys[cq*4+1][row] = yv.y;
    Ys[cq*4+2][row] = yv.z; Ys[cq*4+3][row] = yv.w;
    __syncthreads();
#pragma unroll
    for (int kk = 0; kk < 16; ++kk) {
      float4 av = *(const float4*)(&Xs[kk][ty * 4]);
      float4 bv = *(const float4*)(&Ys[kk][tx * 4]);
      float ar[4] = {av.x, av.y, av.z, av.w};
      float br[4] = {bv.x, bv.y, bv.z, bv.w};
#pragma unroll
      for (int r = 0; r < 4; ++r)
#pragma unroll
        for (int c = 0; c < 4; ++c)
          acc[r][c] += ar[r] * br[c];
    }
  }
  float rx[4], ry[4];
#pragma unroll
  for (int r = 0; r < 4; ++r) rx[r] = rnx[b * 256 + m0 + ty * 4 + r];
#pragma unroll
  for (int c = 0; c < 4; ++c) ry[c] = rny[b * 256 + n0 + tx * 4 + c];
#pragma unroll
  for (int r = 0; r < 4; ++r) {
    int m = m0 + ty * 4 + r;
#pragma unroll
    for (int c = 0; c < 4; ++c) {
      int n = n0 + tx * 4 + c;
      costD[((size_t)b * CD_DIAGS + (m + n)) * 256 + m] = 1.0f - acc[r][c] * rx[r] * ry[c];
    }
  }
}

// ---------------------------------------------------------------------------
// Kernel 3: forward soft-DTW in the log2-scaled domain q = R * (log2e/gv).
// One wave per batch; lane l owns rows i = 4l+1..4l+4; shuffle-only comm.
// Recurrence: q = cost*ig2 + mnq - log2( sum exp2(mnq - q_i) )  -- no per-exp
// multiplies on the serial path.  q streamed to RdG[b][dr][i-1].
// ---------------------------------------------------------------------------
__device__ __forceinline__ void fwd_step(int dr, int l, const float cc[4],
                                         float rp1[4], float rp2[4],
                                         float ig2, float* __restrict__ st) {
  float up1 = __shfl_up(rp1[3], 1);
  float up2 = __shfl_up(rp2[3], 1);
  if (l == 0) { up1 = INFV; up2 = (dr == 2) ? 0.0f : INFV; }
  float val[4];
#pragma unroll
  for (int k = 0; k < 4; ++k) {
    float a  = k ? rp1[k-1] : up1;   // q[i-1][j]
    float bb = rp1[k];               // q[i][j-1]
    float c  = k ? rp2[k-1] : up2;   // q[i-1][j-1]
    float mn = fminf(a, fminf(bb, c));
    float s = EXP2F(mn - a) + EXP2F(mn - bb) + EXP2F(mn - c);
    float v = fmaf(cc[k], ig2, mn - LOG2F(s));
    int j = dr - (4 * l + 1 + k);
    val[k] = ((unsigned)(j - 1) <= 255u) ? v : INFV;
  }
#pragma unroll
  for (int k = 0; k < 4; ++k) { rp2[k] = rp1[k]; rp1[k] = val[k]; }
  float4 s4 = {val[0], val[1], val[2], val[3]};
  *(float4*)st = s4;
}

__global__ void __launch_bounds__(64) fwd_kernel(const float* __restrict__ costD,
                                                 const float* __restrict__ gamma,
                                                 float* __restrict__ RdG,
                                                 float* __restrict__ dist_out) {
  int b = blockIdx.x, l = threadIdx.x;
  float gv = fmaxf(fabsf(gamma[0]), 1e-4f);
  const float LOG2E = 1.4426950408889634f;
  float ig2 = LOG2E / gv;                 // q = R * ig2
  float gl  = gv * 0.6931471805599453f;   // R = q * gl
  const float* cb = costD + (size_t)b * CD_DIAGS * 256;
  float* Rg = RdG + (size_t)b * RD_DIAGS * RD_STRIDE + 4 * l;
  float rp1[4], rp2[4];
#pragma unroll
  for (int k = 0; k < 4; ++k) { rp1[k] = INFV; rp2[k] = INFV; }
  float c0[4], c1[4], c2[4], c3[4];
  ld4(c0, cb + 0 * 256 + 4 * l);
  ld4(c1, cb + 1 * 256 + 4 * l);
  ld4(c2, cb + 2 * 256 + 4 * l);
  ld4(c3, cb + 3 * 256 + 4 * l);
  int dr = 2;
  for (int g = 0; g < 127; ++g) {
    fwd_step(dr + 0, l, c0, rp1, rp2, ig2, Rg + (size_t)(dr + 0) * RD_STRIDE);
    ld4(c0, cb + (size_t)(dr + 2) * 256 + 4 * l);
    fwd_step(dr + 1, l, c1, rp1, rp2, ig2, Rg + (size_t)(dr + 1) * RD_STRIDE);
    ld4(c1, cb + (size_t)(dr + 3) * 256 + 4 * l);
    fwd_step(dr + 2, l, c2, rp1, rp2, ig2, Rg + (size_t)(dr + 2) * RD_STRIDE);
    ld4(c2, cb + (size_t)(dr + 4) * 256 + 4 * l);
    fwd_step(dr + 3, l, c3, rp1, rp2, ig2, Rg + (size_t)(dr + 3) * RD_STRIDE);
    ld4(c3, cb + (size_t)(dr + 5) * 256 + 4 * l);
    dr += 4;
  }
  // dr == 510: tail; FIFO already holds cost diags 508,509,510
  fwd_step(510, l, c0, rp1, rp2, ig2, Rg + (size_t)510 * RD_STRIDE);
  fwd_step(511, l, c1, rp1, rp2, ig2, Rg + (size_t)511 * RD_STRIDE);
  fwd_step(512, l, c2, rp1, rp2, ig2, Rg + (size_t)512 * RD_STRIDE);
  if (l == 63) dist_out[b] = rp1[3] * gl;   // distance = R[256][256]
}

// ---------------------------------------------------------------------------
// Kernel 3.5: precompute ALL backward weights (massively parallel).
// For target cell (i,j) (1-based), diag dr=i+j:
//   wd = exp2(clamp(q[i+1][j+1] - c[i+1][j+1]*ig2 - q[i][j]))   (0 if OOB)
//   wn = exp2(clamp(q[i+1][j]   - c[i+1][j]  *ig2 - q[i][j]))   (0 if OOB)
//   wr = exp2(clamp(q[i][j+1]   - c[i][j+1]  *ig2 - q[i][j]))   (0 if OOB)
// Validity/boundary masking is folded into the weights (invalid cell -> 0),
// so the serial bwd kernel is pure FMA.
// ---------------------------------------------------------------------------
__global__ void __launch_bounds__(256) weights_kernel(const float* __restrict__ RdG,
                                                      const float* __restrict__ costD,
                                                      const float* __restrict__ gamma,
                                                      float* __restrict__ WD,
                                                      float* __restrict__ WN,
                                                      float* __restrict__ WR) {
  int b = blockIdx.y;
  int dr = blockIdx.x + 2;          // 2..512
  int t = threadIdx.x;
  int i = t + 1, j = dr - i;
  const float* Rg = RdG + (size_t)b * RD_DIAGS * RD_STRIDE;
  const float* cb = costD + (size_t)b * CD_DIAGS * 256;
  float gv = fmaxf(fabsf(gamma[0]), 1e-4f);
  const float LOG2E = 1.4426950408889634f;
  float ig2 = LOG2E / gv;
  const float CL = 50.0f * LOG2E;
  float qc = Rg[(size_t)dr * RD_STRIDE + i - 1];
  int dp2 = min(dr + 2, 513), dp1 = min(dr + 1, 513);
  float qd = Rg[(size_t)dp2 * RD_STRIDE + i];
  float qn = Rg[(size_t)dp1 * RD_STRIDE + i];
  float qr = Rg[(size_t)dp1 * RD_STRIDE + i - 1];
  float cd = cb[(size_t)min(dr, 511) * 256 + i];   // cost 0-based (i, j)
  float cn = cb[(size_t)(dr - 1) * 256 + i];       // cost 0-based (i, j-1)
  float cr = cb[(size_t)(dr - 1) * 256 + i - 1];   // cost 0-based (i-1, j)
  float ad = fminf(fmaxf(fmaf(-cd, ig2, qd) - qc, -CL), CL);
  float an = fminf(fmaxf(fmaf(-cn, ig2, qn) - qc, -CL), CL);
  float ar = fminf(fmaxf(fmaf(-cr, ig2, qr) - qc, -CL), CL);
  bool vt = (j >= 1) && (j <= 256);
  float wd = (vt && i <= 255 && j <= 255) ? EXP2F(ad) : 0.0f;
  float wn = (vt && i <= 255) ? EXP2F(an) : 0.0f;
  float wr = (vt && j <= 255) ? EXP2F(ar) : 0.0f;
  size_t o = ((size_t)b * WD_DIAGS + (dr - 2)) * 256 + t;
  WD[o] = wd; WN[o] = wn; WR[o] = wr;
}

// ---------------------------------------------------------------------------
// Kernel 4: lean backward recurrence.  One wave per batch; per step only
//   e[i][j] = E[i+1][j+1]*wd + E[i+1][j]*wn + E[i][j+1]*wr
// (weights preloaded via 4-deep register FIFOs; all masking is in weights).
// E stored in diag layout EdG[b][dr-2][i-1].
// ---------------------------------------------------------------------------
__device__ __forceinline__ void bstep(int l,
    const float wd[4], const float wn[4], const float wr[4],
    float eN[4], float eN2[4], float* __restrict__ st) {
  float eNu  = __shfl_down(eN[0], 1);
  float eN2u = __shfl_down(eN2[0], 1);
  float e[4];
#pragma unroll
  for (int k = 0; k < 4; ++k) {
    float ed = (k < 3) ? eN2[k+1] : eN2u;   // E[i+1][j+1]
    float en = (k < 3) ? eN[k+1]  : eNu;    // E[i+1][j]
    float er = eN[k];                        // E[i][j+1]
    e[k] = ed * wd[k] + en * wn[k] + er * wr[k];
  }
#pragma unroll
  for (int k = 0; k < 4; ++k) { eN2[k] = eN[k]; eN[k] = e[k]; }
  float4 s4 = {e[0], e[1], e[2], e[3]};
  *(float4*)st = s4;
}

__global__ void __launch_bounds__(64) bwd_kernel(const float* __restrict__ WD,
                                                 const float* __restrict__ WN,
                                                 const float* __restrict__ WR,
                                                 float* __restrict__ EdG) {
  int b = blockIdx.x, l = threadIdx.x;
  const float* wdb = WD + (size_t)b * WD_DIAGS * 256 + 4 * l;
  const float* wnb = WN + (size_t)b * WD_DIAGS * 256 + 4 * l;
  const float* wrb = WR + (size_t)b * WD_DIAGS * 256 + 4 * l;
  float* Eg = EdG + (size_t)b * WD_DIAGS * 256;
  float eN[4] = {0.f, 0.f, 0.f, 0.f}, eN2[4] = {0.f, 0.f, 0.f, 0.f};
  if (l == 63) { eN[3] = 1.0f; Eg[510 * 256 + 255] = 1.0f; }
  // current-step weights + 4-deep FIFO (wIdx = dr-2; dr starts at 511)
  float d_[4], n_[4], r_[4];
  float fd0[4], fd1[4], fd2[4], fd3[4];
  float fn0[4], fn1[4], fn2[4], fn3[4];
  float fr0[4], fr1[4], fr2[4], fr3[4];
  ld4(d_,  wdb + (size_t)509 * 256); ld4(n_,  wnb + (size_t)509 * 256); ld4(r_,  wrb + (size_t)509 * 256);
  ld4(fd0, wdb + (size_t)508 * 256); ld4(fn0, wnb + (size_t)508 * 256); ld4(fr0, wrb + (size_t)508 * 256);
  ld4(fd1, wdb + (size_t)507 * 256); ld4(fn1, wnb + (size_t)507 * 256); ld4(fr1, wrb + (size_t)507 * 256);
  ld4(fd2, wdb + (size_t)506 * 256); ld4(fn2, wnb + (size_t)506 * 256); ld4(fr2, wrb + (size_t)506 * 256);
  ld4(fd3, wdb + (size_t)505 * 256); ld4(fn3, wnb + (size_t)505 * 256); ld4(fr3, wrb + (size_t)505 * 256);
  int dr = 511;
  for (int g = 0; g < 127; ++g) {
    bstep(l, d_, n_, r_, eN, eN2, Eg + (size_t)(dr - 2) * 256 + 4 * l);
    cp4(d_, fd0); cp4(n_, fn0); cp4(r_, fr0);
    { int w = max(dr - 7, 0);
      ld4(fd0, wdb + (size_t)w * 256); ld4(fn0, wnb + (size_t)w * 256); ld4(fr0, wrb + (size_t)w * 256); }
    bstep(l, d_, n_, r_, eN, eN2, Eg + (size_t)(dr - 3) * 256 + 4 * l);
    cp4(d_, fd1); cp4(n_, fn1); cp4(r_, fr1);
    { int w = max(dr - 8, 0);
      ld4(fd1, wdb + (size_t)w * 256); ld4(fn1, wnb + (size_t)w * 256); ld4(fr1, wrb + (size_t)w * 256); }
    bstep(l, d_, n_, r_, eN, eN2, Eg + (size_t)(dr - 4) * 256 + 4 * l);
    cp4(d_, fd2); cp4(n_, fn2); cp4(r_, fr2);
    { int w = max(dr - 9, 0);
      ld4(fd2, wdb + (size_t)w * 256); ld4(fn2, wnb + (size_t)w * 256); ld4(fr2, wrb + (size_t)w * 256); }
    bstep(l, d_, n_, r_, eN, eN2, Eg + (size_t)(dr - 5) * 256 + 4 * l);
    cp4(d_, fd3); cp4(n_, fn3); cp4(r_, fr3);
    { int w = max(dr - 10, 0);
      ld4(fd3, wdb + (size_t)w * 256); ld4(fn3, wnb + (size_t)w * 256); ld4(fr3, wrb + (size_t)w * 256); }
    dr -= 4;
  }
  // dr == 3: steps 3 and 2; f0 slots hold wIdx 0
  bstep(l, d_, n_, r_, eN, eN2, Eg + (size_t)1 * 256 + 4 * l);
  cp4(d_, fd0); cp4(n_, fn0); cp4(r_, fr0);
  bstep(l, d_, n_, r_, eN, eN2, Eg + (size_t)0 * 256 + 4 * l);
}

// ---------------------------------------------------------------------------
// Kernel 5: diagonal -> row-major transpose of the alignment.
// ---------------------------------------------------------------------------
__global__ void __launch_bounds__(256) transpose_kernel(const float* __restrict__ EdG,
                                                        float* __restrict__ out) {
  int b = blockIdx.z, mt = blockIdx.y, nt = blockIdx.x;
  int m0 = mt * 64, n0 = nt * 64;
  __shared__ float T[127][65];
  const float* Eg = EdG + (size_t)b * WD_DIAGS * 256;
  int dc0 = m0 + n0;
  for (int k = threadIdx.x; k < 127 * 64; k += 256) {
    int dcl = k >> 6, mm = k & 63;
    T[dcl][mm] = Eg[(size_t)(dc0 + dcl) * 256 + m0 + mm];
  }
  __syncthreads();
  float* ob = out + ((size_t)b * 256 + m0) * 256 + n0;
  for (int k = threadIdx.x; k < 4096; k += 256) {
    int r = k >> 6, c = k & 63;
    ob[(size_t)r * 256 + c] = T[r + c][r];
  }
}

// ---------------------------------------------------------------------------
// Workspace layout (floats), ~21.1 MB total:
//   rnx   @ 0                (2048)
//   rny   @ 2048             (2048)
//   costD @ 4096             8*512*256 = 1,048,576   (reused as EdG by bwd)
//   RdG   @ +costD           8*514*260 = 1,069,120   (q = R*log2e/gv)
//   WD/WN/WR @ +RdG          3 * 8*512*256
// EdG aliases costD: costD is dead after weights_kernel; same-stream order
// guarantees weights_kernel completes before bwd writes EdG.
// d_out: alignment [0 .. 524287], distance [524288 .. 524295].
// ---------------------------------------------------------------------------
extern "C" void kernel_launch(void* const* d_in, const int* in_sizes, int n_in,
                              void* d_out, int out_size, void* d_ws, size_t ws_size,
                              hipStream_t stream) {
  const float* x = (const float*)d_in[0];
  const float* y = (const float*)d_in[1];
  const float* gamma = (const float*)d_in[2];
  float* out = (float*)d_out;
  float* ws = (float*)d_ws;

  float* rnx   = ws;
  float* rny   = ws + 2048;
  float* costD = ws + 4096;
  float* RdG   = costD + (size_t)8 * CD_DIAGS * 256;
  float* WDp   = RdG   + (size_t)8 * RD_DIAGS * RD_STRIDE;
  float* WNp   = WDp   + (size_t)8 * WD_DIAGS * 256;
  float* WRp   = WNp   + (size_t)8 * WD_DIAGS * 256;
  float* EdG   = costD;   // alias: costD dead after weights_kernel

  norms_kernel<<<1024, 256, 0, stream>>>(x, y, rnx, rny);
  cost_gemm<<<dim3(4, 4, 8), 256, 0, stream>>>(x, y, rnx, rny, costD);
  fwd_kernel<<<8, 64, 0, stream>>>(costD, gamma, RdG, out + 524288);
  weights_kernel<<<dim3(511, 8), 256, 0, stream>>>(RdG, costD, gamma, WDp, WNp, WRp);
  bwd_kernel<<<8, 64, 0, stream>>>(WDp, WNp, WRp, EdG);
  transpose_kernel<<<dim3(4, 4, 8), 256, 0, stream>>>(EdG, out);
}

// Round 5
// 243.968 us; speedup vs baseline: 1.8331x; 1.1076x over previous
//
#include <hip/hip_runtime.h>

// Problem constants: B=8, M=N=256, D=512
#define INFV 1.0e8f

// Raw HW transcendentals: v_exp_f32 is 2^x, v_log_f32 is log2(x).
#define EXP2F(x) __builtin_amdgcn_exp2f(x)
#define LOG2F(x) __builtin_amdgcn_logf(x)

__device__ __forceinline__ void ld4(float d[4], const float* p) {
  float4 v = *(const float4*)p;
  d[0] = v.x; d[1] = v.y; d[2] = v.z; d[3] = v.w;
}

// ---------------------------------------------------------------------------
// Kernel 1: inverse row norms.  rn = 1 / max(||row||, 1e-8)
// ---------------------------------------------------------------------------
__global__ void __launch_bounds__(256) norms_kernel(const float* __restrict__ x,
                                                    const float* __restrict__ y,
                                                    float* __restrict__ rnx,
                                                    float* __restrict__ rny) {
  int g = blockIdx.x * 4 + (threadIdx.x >> 6);
  int lane = threadIdx.x & 63;
  const float* src; float* dst; int row;
  if (g < 2048) { src = x; dst = rnx; row = g; }
  else          { src = y; dst = rny; row = g - 2048; }
  const float* p = src + (size_t)row * 512;
  float4 v0 = *(const float4*)(p + lane * 4);
  float4 v1 = *(const float4*)(p + 256 + lane * 4);
  float s = v0.x*v0.x + v0.y*v0.y + v0.z*v0.z + v0.w*v0.w
          + v1.x*v1.x + v1.y*v1.y + v1.z*v1.z + v1.w*v1.w;
#pragma unroll
  for (int o = 32; o > 0; o >>= 1) s += __shfl_xor(s, o, 64);
  if (lane == 0) dst[row] = 1.0f / fmaxf(sqrtf(s), 1e-8f);
}

// ---------------------------------------------------------------------------
// Kernel 2: cost GEMM -> COLUMN-MAJOR layout costC[b][n][m] (stride 256).
// 64x64 tile / 256 threads / 4x4 micro-tile, fp32 vector ALU.
// Epilogue: per (c) a float4 over m -> 16B column-segment stores.
// ---------------------------------------------------------------------------
__global__ void __launch_bounds__(256) cost_gemm(const float* __restrict__ x,
                                                 const float* __restrict__ y,
                                                 const float* __restrict__ rnx,
                                                 const float* __restrict__ rny,
                                                 float* __restrict__ costC) {
  int b = blockIdx.z, mt = blockIdx.y, nt = blockIdx.x;
  int m0 = mt * 64, n0 = nt * 64;
  __shared__ float Xs[16][68];
  __shared__ float Ys[16][68];
  int tid = threadIdx.x;
  int row = tid >> 2, cq = tid & 3;
  int tx = tid & 15, ty = tid >> 4;
  const float* xb = x + ((size_t)b * 256 + m0) * 512;
  const float* yb = y + ((size_t)b * 256 + n0) * 512;
  float acc[4][4] = {};
  for (int k0 = 0; k0 < 512; k0 += 16) {
    float4 xv = *(const float4*)(xb + (size_t)row * 512 + k0 + cq * 4);
    float4 yv = *(const float4*)(yb + (size_t)row * 512 + k0 + cq * 4);
    __syncthreads();
    Xs[cq*4+0][row] = xv.x; Xs[cq*4+1][row] = xv.y;
    Xs[cq*4+2][row] = xv.z; Xs[cq*4+3][row] = xv.w;
    Ys[cq*4+0][row] = yv.x; Ys[cq*4+1][row] = yv.y;
    Ys[cq*4+2][row] = yv.z; Ys[cq*4+3][row] = yv.w;
    __syncthreads();
#pragma unroll
    for (int kk = 0; kk < 16; ++kk) {
      float4 av = *(const float4*)(&Xs[kk][ty * 4]);
      float4 bv = *(const float4*)(&Ys[kk][tx * 4]);
      float ar[4] = {av.x, av.y, av.z, av.w};
      float br[4] = {bv.x, bv.y, bv.z, bv.w};
#pragma unroll
      for (int r = 0; r < 4; ++r)
#pragma unroll
        for (int c = 0; c < 4; ++c)
          acc[r][c] += ar[r] * br[c];
    }
  }
  float rx[4], ry[4];
#pragma unroll
  for (int r = 0; r < 4; ++r) rx[r] = rnx[b * 256 + m0 + ty * 4 + r];
#pragma unroll
  for (int c = 0; c < 4; ++c) ry[c] = rny[b * 256 + n0 + tx * 4 + c];
  float* cb = costC + (size_t)b * 65536;
#pragma unroll
  for (int c = 0; c < 4; ++c) {
    int n = n0 + tx * 4 + c;
    float4 st = {1.0f - acc[0][c] * rx[0] * ry[c],
                 1.0f - acc[1][c] * rx[1] * ry[c],
                 1.0f - acc[2][c] * rx[2] * ry[c],
                 1.0f - acc[3][c] * rx[3] * ry[c]};
    *(float4*)(cb + (size_t)n * 256 + m0 + ty * 4) = st;
  }
}

// ---------------------------------------------------------------------------
// Kernel 3: forward soft-DTW, COLUMN-STRIP traversal, q = R * (log2e/gv).
// One wave per batch.  Lane l owns 0-based rows 4l..4l+3 and walks columns
// left->right, skewed: at slot s lane l processes column j1 = s - l.
// Per slot: one shfl_up (lane l-1's bottom-row value), a 4-cell top-down
// chain, one float4 cost load (FIFO), one float4 q store.  319 live slots
// (vs 511 anti-diagonal steps) -- fewer serial latency round-trips.
// q stored column-major qC[b][j1][r] (stride 256).
// ---------------------------------------------------------------------------
__device__ __forceinline__ void fcol_step(int s, int l, const float cc[4],
                                          float pc[4], float& val3,
                                          float& upPrev, float ig2,
                                          float* __restrict__ qb) {
  int j1 = s - l;
  bool act = (j1 >= 0) && (j1 <= 255);
  float up = __shfl_up(val3, 1);   // q[4l-1][j1]  (lane l-1 bottom row, col j1)
  float dg = upPrev;               // q[4l-1][j1-1] (same, col j1-1)
  if (l == 0) { up = INFV; dg = (j1 == 0) ? 0.0f : INFV; }
  upPrev = up;
  float pu = up, pd = dg;
  float nv[4];
#pragma unroll
  for (int k = 0; k < 4; ++k) {
    float a  = pu;      // up:   q[i-1][j]   (this column)
    float bb = pc[k];   // left: q[i][j-1]
    float c  = pd;      // diag: q[i-1][j-1]
    float mn = fminf(a, fminf(bb, c));
    float s3 = EXP2F(mn - a) + EXP2F(mn - bb) + EXP2F(mn - c);
    float v = fmaf(cc[k], ig2, mn - LOG2F(s3));
    pd = bb;            // diag for next row = left of this row
    pu = v;             // up for next row = this cell
    nv[k] = v;
  }
  if (act) {
#pragma unroll
    for (int k = 0; k < 4; ++k) pc[k] = nv[k];
    val3 = nv[3];
    float4 st = {nv[0], nv[1], nv[2], nv[3]};
    *(float4*)(qb + (size_t)j1 * 256) = st;
  }
}

__global__ void __launch_bounds__(64) fwd_kernel(const float* __restrict__ costC,
                                                 const float* __restrict__ gamma,
                                                 float* __restrict__ qC,
                                                 float* __restrict__ dist_out) {
  int b = blockIdx.x, l = threadIdx.x;
  float gv = fmaxf(fabsf(gamma[0]), 1e-4f);
  const float LOG2E = 1.4426950408889634f;
  float ig2 = LOG2E / gv;                 // q = R * ig2
  float gl  = gv * 0.6931471805599453f;   // R = q * gl
  const float* cb = costC + (size_t)b * 65536 + 4 * l;
  float* qb = qC + (size_t)b * 65536 + 4 * l;
  float pc[4] = {INFV, INFV, INFV, INFV};   // q[rows][j-1]: column-0 boundary
  float val3 = INFV, upPrev = INFV;
  float c0[4], c1[4], c2[4], c3[4];
#define FCOL(s) ((size_t)min(max((s) - l, 0), 255) * 256)
  ld4(c0, cb + FCOL(0));
  ld4(c1, cb + FCOL(1));
  ld4(c2, cb + FCOL(2));
  ld4(c3, cb + FCOL(3));
  for (int g = 0; g < 80; ++g) {
    int s = g * 4;
    fcol_step(s + 0, l, c0, pc, val3, upPrev, ig2, qb);
    ld4(c0, cb + FCOL(s + 4));
    fcol_step(s + 1, l, c1, pc, val3, upPrev, ig2, qb);
    ld4(c1, cb + FCOL(s + 5));
    fcol_step(s + 2, l, c2, pc, val3, upPrev, ig2, qb);
    ld4(c2, cb + FCOL(s + 6));
    fcol_step(s + 3, l, c3, pc, val3, upPrev, ig2, qb);
    ld4(c3, cb + FCOL(s + 7));
  }
#undef FCOL
  if (l == 63) dist_out[b] = val3 * gl;   // q[255][255] -> R[256][256]
}

// ---------------------------------------------------------------------------
// Kernel 3.5: backward weights, tile-based, all layouts column-major.
// Target cell 0-based (r, c); rp = min(r+1,255), cp = min(c+1,255):
//   wd = exp2(clamp(q[cp][rp] - cost[cp][rp]*ig2 - q[c][r]))  if r<255 && c<255
//   wn = exp2(clamp(q[c][rp]  - cost[c][rp] *ig2 - q[c][r]))  if r<255
//   wr = exp2(clamp(q[cp][r]  - cost[cp][r] *ig2 - q[c][r]))  if c<255
// Boundary masking folded into weights (0).  Coalesced along r.
// ---------------------------------------------------------------------------
__global__ void __launch_bounds__(256) weights_kernel(const float* __restrict__ qC,
                                                      const float* __restrict__ costC,
                                                      const float* __restrict__ gamma,
                                                      float* __restrict__ WDc,
                                                      float* __restrict__ WNc,
                                                      float* __restrict__ WRc) {
  int b = blockIdx.z;
  int t = threadIdx.x;
  int r = blockIdx.y * 64 + (t & 63);
  int cbase = blockIdx.x * 64 + (t >> 6) * 16;
  int rp = min(r + 1, 255);
  float gv = fmaxf(fabsf(gamma[0]), 1e-4f);
  const float LOG2E = 1.4426950408889634f;
  float ig2 = LOG2E / gv;
  const float CL = 50.0f * LOG2E;
  const float* q  = qC    + (size_t)b * 65536;
  const float* co = costC + (size_t)b * 65536;
  float* wd_ = WDc + (size_t)b * 65536;
  float* wn_ = WNc + (size_t)b * 65536;
  float* wr_ = WRc + (size_t)b * 65536;
  // carried streams: qc(c)=q[c][r], qn(c)=q[c][rp], cn(c)=cost[c][rp]
  float qcv = q[(size_t)cbase * 256 + r];
  float qnv = q[(size_t)cbase * 256 + rp];
  float cnv = co[(size_t)cbase * 256 + rp];
#pragma unroll 4
  for (int k = 0; k < 16; ++k) {
    int c = cbase + k;
    int cp = min(c + 1, 255);
    float qdv = q[(size_t)cp * 256 + rp];
    float qrv = q[(size_t)cp * 256 + r];
    float cdv = co[(size_t)cp * 256 + rp];
    float crv = co[(size_t)cp * 256 + r];
    float ad = fminf(fmaxf(fmaf(-cdv, ig2, qdv) - qcv, -CL), CL);
    float an = fminf(fmaxf(fmaf(-cnv, ig2, qnv) - qcv, -CL), CL);
    float ar = fminf(fmaxf(fmaf(-crv, ig2, qrv) - qcv, -CL), CL);
    float wd = (r < 255 && c < 255) ? EXP2F(ad) : 0.0f;
    float wn = (r < 255) ? EXP2F(an) : 0.0f;
    float wr = (c < 255) ? EXP2F(ar) : 0.0f;
    size_t o = (size_t)c * 256 + r;
    wd_[o] = wd; wn_[o] = wn; wr_[o] = wr;
    qcv = qrv; qnv = qdv; cnv = cdv;   // carry to column c+1
  }
}

// ---------------------------------------------------------------------------
// Kernel 4: backward recurrence, COLUMN-STRIP right->left.
//   E[r][c] = E[r+1][c+1]*wd + E[r+1][c]*wn + E[r][c+1]*wr,  E[255][255]=1.
// Lane l owns rows 4l..4l+3, processes cells bottom-up; lane l+1 runs one
// column ahead (shfl_down of its top-row value).  E stored column-major.
// ---------------------------------------------------------------------------
__device__ __forceinline__ void bcol_step(int s, int l,
    const float wd[4], const float wn[4], const float wr[4],
    float pcE[4], float& topVal, float& dnPrev, float* __restrict__ Eb) {
  int c = 318 - s - l;
  bool act = (c >= 0) && (c <= 255);
  float dnS  = __shfl_down(topVal, 1);  // E[4l+4][c]   (lane l+1 top row)
  float drt0 = dnPrev;                   // E[4l+4][c+1]
  if (l == 63) { dnS = 0.0f; drt0 = 0.0f; }
  dnPrev = dnS;
  float dn = dnS, drt = drt0;
  float nv[4];
#pragma unroll
  for (int k = 3; k >= 0; --k) {
    float rt = pcE[k];                   // E[r][c+1]
    float v = drt * wd[k] + dn * wn[k] + rt * wr[k];
    if (k == 3) { if (l == 63 && c == 255) v = 1.0f; }   // seed E[255][255]
    drt = rt;     // E[r][c+1] becomes E[(r-1)+1][c+1]
    dn  = v;      // this cell becomes E[(r-1)+1][c]
    nv[k] = v;
  }
  if (act) {
#pragma unroll
    for (int k = 0; k < 4; ++k) pcE[k] = nv[k];
    topVal = nv[0];
    float4 st = {nv[0], nv[1], nv[2], nv[3]};
    *(float4*)(Eb + (size_t)c * 256) = st;
  }
}

__global__ void __launch_bounds__(64) bwd_kernel(const float* __restrict__ WDc,
                                                 const float* __restrict__ WNc,
                                                 const float* __restrict__ WRc,
                                                 float* __restrict__ EC) {
  int b = blockIdx.x, l = threadIdx.x;
  const float* wdb = WDc + (size_t)b * 65536 + 4 * l;
  const float* wnb = WNc + (size_t)b * 65536 + 4 * l;
  const float* wrb = WRc + (size_t)b * 65536 + 4 * l;
  float* Eb = EC + (size_t)b * 65536 + 4 * l;
  float pcE[4] = {0.f, 0.f, 0.f, 0.f};   // E[rows][c+1]: column-256 boundary
  float topVal = 0.0f, dnPrev = 0.0f;
  float d0[4], d1[4], d2[4], d3[4];
  float n0[4], n1[4], n2[4], n3[4];
  float r0[4], r1[4], r2[4], r3[4];
#define WCOL(s) ((size_t)min(max(318 - (s) - l, 0), 255) * 256)
  ld4(d0, wdb + WCOL(0)); ld4(n0, wnb + WCOL(0)); ld4(r0, wrb + WCOL(0));
  ld4(d1, wdb + WCOL(1)); ld4(n1, wnb + WCOL(1)); ld4(r1, wrb + WCOL(1));
  ld4(d2, wdb + WCOL(2)); ld4(n2, wnb + WCOL(2)); ld4(r2, wrb + WCOL(2));
  ld4(d3, wdb + WCOL(3)); ld4(n3, wnb + WCOL(3)); ld4(r3, wrb + WCOL(3));
  for (int g = 0; g < 80; ++g) {
    int s = g * 4;
    bcol_step(s + 0, l, d0, n0, r0, pcE, topVal, dnPrev, Eb);
    ld4(d0, wdb + WCOL(s + 4)); ld4(n0, wnb + WCOL(s + 4)); ld4(r0, wrb + WCOL(s + 4));
    bcol_step(s + 1, l, d1, n1, r1, pcE, topVal, dnPrev, Eb);
    ld4(d1, wdb + WCOL(s + 5)); ld4(n1, wnb + WCOL(s + 5)); ld4(r1, wrb + WCOL(s + 5));
    bcol_step(s + 2, l, d2, n2, r2, pcE, topVal, dnPrev, Eb);
    ld4(d2, wdb + WCOL(s + 6)); ld4(n2, wnb + WCOL(s + 6)); ld4(r2, wrb + WCOL(s + 6));
    bcol_step(s + 3, l, d3, n3, r3, pcE, topVal, dnPrev, Eb);
    ld4(d3, wdb + WCOL(s + 7)); ld4(n3, wnb + WCOL(s + 7)); ld4(r3, wrb + WCOL(s + 7));
  }
#undef WCOL
}

// ---------------------------------------------------------------------------
// Kernel 5: plain 2D transpose: out[b][m][n] = EC[b][n*256 + m].
// LDS 64x65 tile, both global phases coalesced.
// ---------------------------------------------------------------------------
__global__ void __launch_bounds__(256) transpose_kernel(const float* __restrict__ EC,
                                                        float* __restrict__ out) {
  int b = blockIdx.z, mt = blockIdx.y, nt = blockIdx.x;
  int m0 = mt * 64, n0 = nt * 64;
  __shared__ float T[64][65];
  const float* Eb = EC + (size_t)b * 65536;
  for (int k = threadIdx.x; k < 4096; k += 256) {
    int nn = k >> 6, mm = k & 63;
    T[nn][mm] = Eb[(size_t)(n0 + nn) * 256 + m0 + mm];
  }
  __syncthreads();
  float* ob = out + ((size_t)b * 256 + m0) * 256 + n0;
  for (int k = threadIdx.x; k < 4096; k += 256) {
    int r = k >> 6, c = k & 63;
    ob[(size_t)r * 256 + c] = T[c][r];
  }
}

// ---------------------------------------------------------------------------
// Workspace layout (floats), ~12.6 MB total (all matrices column-major,
// 65536 floats per batch, stride 256):
//   rnx @ 0 (2048) | rny @ 2048 (2048) | costC @ 4096 | qC | WDc | WNc | WRc | EC
// d_out: alignment [0 .. 524287], distance [524288 .. 524295].
// ---------------------------------------------------------------------------
extern "C" void kernel_launch(void* const* d_in, const int* in_sizes, int n_in,
                              void* d_out, int out_size, void* d_ws, size_t ws_size,
                              hipStream_t stream) {
  const float* x = (const float*)d_in[0];
  const float* y = (const float*)d_in[1];
  const float* gamma = (const float*)d_in[2];
  float* out = (float*)d_out;
  float* ws = (float*)d_ws;

  const size_t MAT = (size_t)8 * 65536;
  float* rnx   = ws;
  float* rny   = ws + 2048;
  float* costC = ws + 4096;
  float* qC    = costC + MAT;
  float* WDc   = qC    + MAT;
  float* WNc   = WDc   + MAT;
  float* WRc   = WNc   + MAT;
  float* EC    = WRc   + MAT;

  norms_kernel<<<1024, 256, 0, stream>>>(x, y, rnx, rny);
  cost_gemm<<<dim3(4, 4, 8), 256, 0, stream>>>(x, y, rnx, rny, costC);
  fwd_kernel<<<8, 64, 0, stream>>>(costC, gamma, qC, out + 524288);
  weights_kernel<<<dim3(4, 4, 8), 256, 0, stream>>>(qC, costC, gamma, WDc, WNc, WRc);
  bwd_kernel<<<8, 64, 0, stream>>>(WDc, WNc, WRc, EC);
  transpose_kernel<<<dim3(4, 4, 8), 256, 0, stream>>>(EC, out);
}